// Round 2
// baseline (672.502 us; speedup 1.0000x reference)
//
#include <hip/hip_runtime.h>
#include <math.h>

// Algebraic collapse: out depends on h = X@We + be only through h@Wc and h@Wf.
//   logits[:, 0:20]  = X @ (We@Wc) + (be@Wc + bc)
//   logits[:, 20:40] = X @ (We@Wf) + (be@Wf + bf)
// K0: zero Weff, fold bias2 = [be@Wc + bc | be@Wf + bf]
// K1: Weff = We @ [Wc|Wf]   (panel_gemm<1,false>, 4-way block-K atomic split)
// K2: out  = epilogue(X @ Weff + bias2)   (panel_gemm<4,true>)
//
// Round-2 redesign: lanes span K. X is read directly from global, coalesced,
// touched once (no X LDS tile, no per-chunk barriers). B is staged per 512-k
// super-chunk into a paired LDS panel [cj][2k] (pad stride 1028) and read as
// contiguous ds_read_b128 (conflict-free, in-order lgkmcnt). This removes
// SMEM (s_load) from the inner loop entirely -- round-1's stall source:
// SMEM shares lgkmcnt with LDS and returns out-of-order, so every B-batch
// consume forced a full lgkmcnt(0) drain of the ds pipeline.

typedef float v2f __attribute__((ext_vector_type(2)));
typedef float v4f __attribute__((ext_vector_type(4)));

#define KD    2048
#define NCLS  20
#define NC2   40
#define SMARG 0.31f

// ws layout (floats): Weff[2048*40] row-major, then bias2[40]
#define WEFF_OFF 0
#define BIAS_OFF 81920

#define PROW  1028                  // panel row stride (1024 + 4 pad): bank-spread
#define PANEL_FLOATS (20 * PROW)    // 20560 floats = 82240 B (also covers Hacc 5248)
#define HROW  164                   // Hacc row: 40 cols x 4 partials + 4 pad (41 quads)

static __device__ __forceinline__ v2f fma2(v2f a, v2f b, v2f c) {
#if __has_builtin(__builtin_elementwise_fma)
    return __builtin_elementwise_fma(a, b, c);   // -> v_pk_fma_f32
#else
    v2f r; r[0] = fmaf(a[0], b[0], c[0]); r[1] = fmaf(a[1], b[1], c[1]); return r;
#endif
}

// ---------------- K0: zero Weff, fold bias2 --------------------------------
__global__ __launch_bounds__(256)
void k0_prep(const float* __restrict__ Wc, const float* __restrict__ bc,
             const float* __restrict__ Wf, const float* __restrict__ bf,
             const float* __restrict__ be, float* __restrict__ ws)
{
    const int b = blockIdx.x;
    const int t = threadIdx.x;
    if (b < 80) {                                   // zero Weff: 80*256*4 = 81920
        v4f z = {0.f, 0.f, 0.f, 0.f};
        *(v4f*)&ws[WEFF_OFF + 4 * (b * 256 + t)] = z;
    } else {                                        // bias2[col], col = b-80
        const int col = b - 80;
        const float* Wp = (col < NCLS) ? Wc : Wf;
        const int cc = (col < NCLS) ? col : col - NCLS;
        float p = 0.f;
        for (int n = t; n < KD; n += 256)
            p = fmaf(be[n], Wp[n * NCLS + cc], p);
        __shared__ float red[256];
        red[t] = p;
        __syncthreads();
        for (int s = 128; s > 0; s >>= 1) {
            if (t < s) red[t] += red[t + s];
            __syncthreads();
        }
        if (t == 0)
            ws[BIAS_OFF + col] = red[0] + ((col < NCLS) ? bc[cc] : bf[cc]);
    }
}

// ---------------- panel GEMM: C[M,40] (+=) A[M,2048] @ B[2048,40] ----------
// Block: 1024 thr = 16 waves = 2 col-groups(20 cols) x 8 row-groups(4 rows).
// Lanes span k (2 consecutive k per lane per step of 128 k). acc2[r][j2] is a
// v2f over adjacent cols -> v_pk_fma_f32 with a float4 B fragment
// (B[k][2j2],B[k][2j2+1],B[k+1][2j2],B[k+1][2j2+1]) from the paired panel.
// End: 4-stage recursive-halving shfl reduce (16-lane groups, 5 values/lane),
// 4 partials -> LDS Hacc -> 32 row-lanes finalize.
// FUSED=false: B0/B1 = Wc/Wf (stride 20), atomicAdd into Cacc (Weff).
// FUSED=true:  B0 = Weff (stride 40), fused softmax/threshold epilogue.
template<int NSUP, bool FUSED>
__global__ __launch_bounds__(1024)
void panel_gemm(const float* __restrict__ A,
                const float* __restrict__ B0,
                const float* __restrict__ B1,
                float* __restrict__ Cacc,
                const float* __restrict__ bias2,
                float* __restrict__ outp)
{
    __shared__ __align__(16) float smem[PANEL_FLOATS];
    const int tid  = threadIdx.x;
    const int lane = tid & 63;
    const int w    = tid >> 6;          // wave 0..15
    const int cg   = w & 1;             // col-group: cols [cg*20, cg*20+20)
    const int rg   = w >> 1;            // row-group: rows [rg*4, rg*4+4)

    int m0, kbase;
    if (FUSED) { m0 = blockIdx.x * 32;              kbase = 0; }
    else       { m0 = (int)(blockIdx.x >> 2) * 32;  kbase = (int)(blockIdx.x & 3) * 512; }

    const float* Arow = A + (size_t)(m0 + rg * 4) * KD + kbase + 2 * lane;

    v2f acc2[4][10];
    #pragma unroll
    for (int r = 0; r < 4; ++r)
        #pragma unroll
        for (int j = 0; j < 10; ++j) acc2[r][j] = (v2f){0.f, 0.f};

    v2f xv[4], xn[4] = {};
    #pragma unroll
    for (int r = 0; r < 4; ++r) xv[r] = *(const v2f*)(Arow + r * KD);

    const int NSTEPS = NSUP * 4;
    for (int sup = 0; sup < NSUP; ++sup) {
        if (sup) __syncthreads();                   // prev-panel readers done
        // ---- stage 512-k paired panel: 10 x (dwordx2 load, ds_write_b64) ----
        {
            const int kb = kbase + sup * 512;
            v2f sv[10];
            #pragma unroll
            for (int it = 0; it < 10; ++it) {
                const int pi = tid + it * 1024;     // < 10240
                const int k = pi / 20, cj = pi % 20;
                const float* src;
                if (FUSED) {
                    src = B0 + (size_t)(kb + k) * 40 + 2 * cj;
                } else {
                    src = (cj < 10) ? (B0 + (size_t)(kb + k) * 20 + 2 * cj)
                                    : (B1 + (size_t)(kb + k) * 20 + 2 * (cj - 10));
                }
                sv[it] = *(const v2f*)src;
            }
            #pragma unroll
            for (int it = 0; it < 10; ++it) {
                const int pi = tid + it * 1024;
                const int k = pi / 20, cj = pi % 20;
                *(v2f*)(smem + cj * PROW + 2 * k) = sv[it];
            }
        }
        __syncthreads();
        // ---- 4 compute steps of 128 k each ----
        #pragma unroll
        for (int st = 0; st < 4; ++st) {
            const int step = sup * 4 + st;
            if (step + 1 < NSTEPS) {                // prefetch next-step X
                #pragma unroll
                for (int r = 0; r < 4; ++r)
                    xn[r] = *(const v2f*)(Arow + r * KD + (step + 1) * 128);
            }
            const float* pb = smem + cg * (10 * PROW) + st * 256 + 4 * lane;
            #pragma unroll
            for (int j2 = 0; j2 < 10; ++j2) {
                v4f bv  = *(const v4f*)(pb + j2 * PROW);   // contiguous b128, 0-conflict
                v2f blo = {bv[0], bv[1]}, bhi = {bv[2], bv[3]};
                #pragma unroll
                for (int r = 0; r < 4; ++r) {
                    v2f x0 = {xv[r][0], xv[r][0]};
                    v2f x1 = {xv[r][1], xv[r][1]};
                    acc2[r][j2] = fma2(x1, bhi, fma2(x0, blo, acc2[r][j2]));
                }
            }
            #pragma unroll
            for (int r = 0; r < 4; ++r) xv[r] = xn[r];
        }
    }

    __syncthreads();                                // panel dead; alias as Hacc
    // ---- recursive-halving reduce-scatter over 16-lane groups ----
    float* v = (float*)acc2;                        // v[r*20 + 2*j2 + p]
    {
        const bool u1 = lane & 1;
        #pragma unroll
        for (int i = 0; i < 40; ++i) {
            float snd = u1 ? v[i] : v[i + 40];
            float rcv = __shfl_xor(snd, 1, 64);
            v[i] = (u1 ? v[i + 40] : v[i]) + rcv;
        }
        const bool u2 = lane & 2;
        #pragma unroll
        for (int i = 0; i < 20; ++i) {
            float snd = u2 ? v[i] : v[i + 20];
            float rcv = __shfl_xor(snd, 2, 64);
            v[i] = (u2 ? v[i + 20] : v[i]) + rcv;
        }
        const bool u4 = lane & 4;
        #pragma unroll
        for (int i = 0; i < 10; ++i) {
            float snd = u4 ? v[i] : v[i + 10];
            float rcv = __shfl_xor(snd, 4, 64);
            v[i] = (u4 ? v[i + 10] : v[i]) + rcv;
        }
        const bool u8 = lane & 8;
        #pragma unroll
        for (int i = 0; i < 5; ++i) {
            float snd = u8 ? v[i] : v[i + 5];
            float rcv = __shfl_xor(snd, 8, 64);
            v[i] = (u8 ? v[i + 5] : v[i]) + rcv;
        }
    }
    // lane owns orig indices base..base+4, base = 40a+20b+10c+5d (a..d = lane bits)
    {
        const int g   = lane >> 4;                          // partial group 0..3
        const int r   = 2 * (lane & 1) + ((lane >> 1) & 1); // base/20
        const int cl0 = 10 * ((lane >> 2) & 1) + 5 * ((lane >> 3) & 1);
        #pragma unroll
        for (int i = 0; i < 5; ++i)
            smem[(rg * 4 + r) * HROW + (cg * 20 + cl0 + i) * 4 + g] = v[i];
    }
    __syncthreads();

    if (tid < 32) {
        float l[40];
        #pragma unroll
        for (int c = 0; c < 40; ++c) {
            v4f q = *(const v4f*)(smem + tid * HROW + c * 4);
            l[c] = (q[0] + q[1]) + (q[2] + q[3]);
        }
        if (FUSED) {
            #pragma unroll
            for (int c = 0; c < 40; ++c) l[c] += bias2[c];
            float mC = l[0];
            #pragma unroll
            for (int c = 1; c < 20; ++c) mC = fmaxf(mC, l[c]);
            float e[20];
            float sC = 0.f;
            #pragma unroll
            for (int c = 0; c < 20; ++c) { e[c] = expf(l[c] - mC); sC += e[c]; }
            float mF = l[20], mnF = l[20];
            #pragma unroll
            for (int c = 21; c < 40; ++c) {
                mF = fmaxf(mF, l[c]);
                mnF = fminf(mnF, l[c]);
            }
            float sF = 0.f;
            #pragma unroll
            for (int c = 20; c < 40; ++c) sF += expf(l[c] - mF);
            float pred  = 1.f / sC;                 // max softmax == exp(0)/sum
            float tau   = expf(mnF - mF) / sF;      // min softmax of flow head
            float scale = (pred >= tau + SMARG) ? pred : 0.f;
            float* op = outp + (size_t)(m0 + tid) * NCLS;
            #pragma unroll
            for (int j = 0; j < 5; ++j) {
                v4f o;
                #pragma unroll
                for (int i = 0; i < 4; ++i) o[i] = e[4 * j + i] * scale;
                *(v4f*)(op + 4 * j) = o;
            }
        } else {
            #pragma unroll
            for (int c = 0; c < 40; ++c)
                atomicAdd(Cacc + (size_t)(m0 + tid) * 40 + c, l[c]);
        }
    }
}

extern "C" void kernel_launch(void* const* d_in, const int* in_sizes, int n_in,
                              void* d_out, int out_size, void* d_ws, size_t ws_size,
                              hipStream_t stream) {
    const float* X  = (const float*)d_in[0];
    const float* We = (const float*)d_in[1];
    const float* be = (const float*)d_in[2];
    const float* Wc = (const float*)d_in[3];
    const float* bc = (const float*)d_in[4];
    const float* Wf = (const float*)d_in[5];
    const float* bf = (const float*)d_in[6];
    float* out = (float*)d_out;
    float* ws  = (float*)d_ws;
    (void)in_sizes; (void)n_in; (void)out_size; (void)ws_size;

    // K0: zero Weff + fold bias2
    k0_prep<<<dim3(120), dim3(256), 0, stream>>>(Wc, bc, Wf, bf, be, ws);
    // K1: Weff = We @ [Wc|Wf]   (64 row-blocks x 4 block-K splits = 256 blocks)
    panel_gemm<1, false><<<dim3(256), dim3(1024), 0, stream>>>(
        We, Wc, Wf, ws + WEFF_OFF, nullptr, nullptr);
    // K2: out = softmax-threshold(X @ Weff + bias2)   (512 blocks x 32 rows)
    panel_gemm<4, true><<<dim3(512), dim3(1024), 0, stream>>>(
        X, ws + WEFF_OFF, nullptr, nullptr, ws + BIAS_OFF, out);
}

// Round 3
// 393.621 us; speedup vs baseline: 1.7085x; 1.7085x over previous
//
#include <hip/hip_runtime.h>
#include <math.h>

// Algebraic collapse: out depends on h = X@We + be only through h@Wc and h@Wf.
//   logits[:, 0:20]  = X @ (We@Wc) + (be@Wc + bc)
//   logits[:, 20:40] = X @ (We@Wf) + (be@Wf + bf)
// K0: zero Weff, fold bias2 = [be@Wc + bc | be@Wf + bf]
// K1: Weff = We @ [Wc|Wf]   (panel_gemm<1,false>, 4-way block-K atomic split)
// K2: out  = epilogue(X @ Weff + bias2)   (panel_gemm<4,true>)
//
// Round-3 fix: round 2's accumulator was demoted to SCRATCH (VGPR_Count=64,
// 1.09 GB of scratch writes/dispatch) because the reduce phase did
// `float* v = (float*)acc2` -- address-taking through a type-punned pointer
// defeats SROA and the array lives in private memory for the WHOLE kernel.
// Now: (a) reduce indexes acc2 via compile-time-constant GEPs only (V(i)
// macro, no pointer cast anywhere); (b) 512-thread blocks with
// __launch_bounds__(512,2) -> 256-VGPR budget that actually fits the
// accumulator (round 2's 1024-thr bounds capped at 128 VGPR, guaranteeing
// pressure); (c) 8 rows/thread halves LDS B-read traffic per output row.

typedef float v2f __attribute__((ext_vector_type(2)));
typedef float v4f __attribute__((ext_vector_type(4)));

#define KD    2048
#define NCLS  20
#define SMARG 0.31f

// ws layout (floats): Weff[2048*40] row-major, then bias2[40]
#define WEFF_OFF 0
#define BIAS_OFF 81920

#define PROW  1028                  // panel row stride floats (1024+4): 16B-aligned
#define PANEL_FLOATS (20 * PROW)    // 20560 floats = 82240 B (Hacc 5248 aliases)
#define HROW  164                   // Hacc row: 40 cols x 4 partials + 4 pad

static __device__ __forceinline__ v2f fma2(v2f a, v2f b, v2f c) {
#if __has_builtin(__builtin_elementwise_fma)
    return __builtin_elementwise_fma(a, b, c);   // -> v_pk_fma_f32
#else
    v2f r; r[0] = fmaf(a[0], b[0], c[0]); r[1] = fmaf(a[1], b[1], c[1]); return r;
#endif
}

// ---------------- K0: zero Weff, fold bias2 --------------------------------
__global__ __launch_bounds__(256)
void k0_prep(const float* __restrict__ Wc, const float* __restrict__ bc,
             const float* __restrict__ Wf, const float* __restrict__ bf,
             const float* __restrict__ be, float* __restrict__ ws)
{
    const int b = blockIdx.x;
    const int t = threadIdx.x;
    if (b < 80) {                                   // zero Weff: 80*256*4 = 81920
        v4f z = {0.f, 0.f, 0.f, 0.f};
        *(v4f*)&ws[WEFF_OFF + 4 * (b * 256 + t)] = z;
    } else {                                        // bias2[col], col = b-80
        const int col = b - 80;
        const float* Wp = (col < NCLS) ? Wc : Wf;
        const int cc = (col < NCLS) ? col : col - NCLS;
        float p = 0.f;
        for (int n = t; n < KD; n += 256)
            p = fmaf(be[n], Wp[n * NCLS + cc], p);
        __shared__ float red[256];
        red[t] = p;
        __syncthreads();
        for (int s = 128; s > 0; s >>= 1) {
            if (t < s) red[t] += red[t + s];
            __syncthreads();
        }
        if (t == 0)
            ws[BIAS_OFF + col] = red[0] + ((col < NCLS) ? bc[cc] : bf[cc]);
    }
}

// ---------------- panel GEMM: C[M,40] (+=) A[M,2048] @ B[2048,40] ----------
// Block: 512 thr = 8 waves = 2 col-groups(20 cols) x 4 row-groups(8 rows).
// Lanes span k (2 consecutive k/lane/step of 128 k). X read directly from
// global, coalesced, touched once. B staged per 512-k super into a paired
// LDS panel [cj][2k] (stride 1028) and read as contiguous ds_read_b128.
// acc2[8][10] v2f -> v_pk_fma_f32; each b128 B-fragment feeds 16 fmas.
// End: 4-stage recursive-halving shfl reduce (16-lane groups) with STATIC
// indexing only, 4 partials -> LDS Hacc -> 32 row-lanes finalize.
template<int NSUP, bool FUSED>
__global__ __launch_bounds__(512, 2)
void panel_gemm(const float* __restrict__ A,
                const float* __restrict__ B0,
                const float* __restrict__ B1,
                float* __restrict__ Cacc,
                const float* __restrict__ bias2,
                float* __restrict__ outp)
{
    __shared__ __align__(16) float smem[PANEL_FLOATS];
    const int tid  = threadIdx.x;
    const int lane = tid & 63;
    const int w    = tid >> 6;          // wave 0..7
    const int cg   = w & 1;             // col-group: cols [cg*20, cg*20+20)
    const int rg   = w >> 1;            // row-group: rows [rg*8, rg*8+8)

    int m0, kbase;
    if (FUSED) { m0 = blockIdx.x * 32;              kbase = 0; }
    else       { m0 = (int)(blockIdx.x >> 2) * 32;  kbase = (int)(blockIdx.x & 3) * 512; }

    const float* Arow = A + (size_t)(m0 + rg * 8) * KD + kbase + 2 * lane;

    v2f acc2[8][10];
    #pragma unroll
    for (int r = 0; r < 8; ++r)
        #pragma unroll
        for (int j = 0; j < 10; ++j) acc2[r][j] = (v2f){0.f, 0.f};

    v2f xv[8], xn[8];
    #pragma unroll
    for (int r = 0; r < 8; ++r) xv[r] = *(const v2f*)(Arow + r * KD);

    const int NSTEPS = NSUP * 4;
    #pragma unroll
    for (int sup = 0; sup < NSUP; ++sup) {
        if (sup) __syncthreads();                   // prev-panel readers done
        // ---- stage 512-k paired panel: 2 batches of 10 (v2f load+write) ----
        const int kb = kbase + sup * 512;
        #pragma unroll
        for (int half = 0; half < 2; ++half) {
            v2f sv[10];
            #pragma unroll
            for (int it = 0; it < 10; ++it) {
                const int pi = tid + (half * 10 + it) * 512;  // < 10240
                const int k = pi / 20, cj = pi % 20;
                const float* src;
                if (FUSED) {
                    src = B0 + (size_t)(kb + k) * 40 + 2 * cj;
                } else {
                    src = (cj < 10) ? (B0 + (size_t)(kb + k) * 20 + 2 * cj)
                                    : (B1 + (size_t)(kb + k) * 20 + 2 * (cj - 10));
                }
                sv[it] = *(const v2f*)src;
            }
            #pragma unroll
            for (int it = 0; it < 10; ++it) {
                const int pi = tid + (half * 10 + it) * 512;
                const int k = pi / 20, cj = pi % 20;
                *(v2f*)(smem + cj * PROW + 2 * k) = sv[it];
            }
        }
        __syncthreads();
        // ---- 4 compute steps of 128 k each ----
        #pragma unroll
        for (int st = 0; st < 4; ++st) {
            const int step = sup * 4 + st;
            if (step + 1 < NSTEPS) {                // prefetch next-step X
                #pragma unroll
                for (int r = 0; r < 8; ++r)
                    xn[r] = *(const v2f*)(Arow + r * KD + (step + 1) * 128);
            }
            const float* pb = smem + cg * (10 * PROW) + st * 256 + 4 * lane;
            #pragma unroll
            for (int j2 = 0; j2 < 10; ++j2) {
                v4f bv  = *(const v4f*)(pb + j2 * PROW);   // contiguous b128
                v2f blo = {bv[0], bv[1]}, bhi = {bv[2], bv[3]};
                #pragma unroll
                for (int r = 0; r < 8; ++r) {
                    v2f x0 = {xv[r][0], xv[r][0]};
                    v2f x1 = {xv[r][1], xv[r][1]};
                    acc2[r][j2] = fma2(x1, bhi, fma2(x0, blo, acc2[r][j2]));
                }
            }
            if (step + 1 < NSTEPS) {
                #pragma unroll
                for (int r = 0; r < 8; ++r) xv[r] = xn[r];
            }
        }
    }

    __syncthreads();                                // panel dead; alias as Hacc

    // ---- recursive-halving reduce-scatter over 16-lane groups -------------
    // 160 values/lane, logical index i = r*20 + (col-in-group); ALL accesses
    // are compile-time-constant GEPs on acc2 (no pointer cast -> stays VGPR).
#define V(i) acc2[(i) / 20][((i) % 20) >> 1][(i) & 1]
    {
        const bool u1 = lane & 1;
        #pragma unroll
        for (int i = 0; i < 80; ++i) {
            float snd = u1 ? V(i) : V(i + 80);
            float rcv = __shfl_xor(snd, 1, 64);
            V(i) = (u1 ? V(i + 80) : V(i)) + rcv;
        }
        const bool u2 = lane & 2;
        #pragma unroll
        for (int i = 0; i < 40; ++i) {
            float snd = u2 ? V(i) : V(i + 40);
            float rcv = __shfl_xor(snd, 2, 64);
            V(i) = (u2 ? V(i + 40) : V(i)) + rcv;
        }
        const bool u4 = lane & 4;
        #pragma unroll
        for (int i = 0; i < 20; ++i) {
            float snd = u4 ? V(i) : V(i + 20);
            float rcv = __shfl_xor(snd, 4, 64);
            V(i) = (u4 ? V(i + 20) : V(i)) + rcv;
        }
        const bool u8 = lane & 8;
        #pragma unroll
        for (int i = 0; i < 10; ++i) {
            float snd = u8 ? V(i) : V(i + 10);
            float rcv = __shfl_xor(snd, 8, 64);
            V(i) = (u8 ? V(i + 10) : V(i)) + rcv;
        }
    }
    // lane holds orig indices base..base+9, base = 80a+40b+20c+10d (lane bits)
    {
        const int a = lane & 1, b = (lane >> 1) & 1;
        const int c = (lane >> 2) & 1, d = (lane >> 3) & 1;
        const int g  = lane >> 4;                   // partial group 0..3
        const int r0 = 4 * a + 2 * b + c;           // row within row-group
        const int c0 = cg * 20 + 10 * d;            // first col
        #pragma unroll
        for (int t = 0; t < 10; ++t)
            smem[(rg * 8 + r0) * HROW + (c0 + t) * 4 + g] = V(t);
    }
#undef V
    __syncthreads();

    if (tid < 32) {
        float l[40];
        #pragma unroll
        for (int cc = 0; cc < 40; ++cc) {
            v4f q = *(const v4f*)(smem + tid * HROW + cc * 4);
            l[cc] = (q[0] + q[1]) + (q[2] + q[3]);
        }
        if (FUSED) {
            #pragma unroll
            for (int cc = 0; cc < 40; ++cc) l[cc] += bias2[cc];
            float mC = l[0];
            #pragma unroll
            for (int cc = 1; cc < 20; ++cc) mC = fmaxf(mC, l[cc]);
            float e[20];
            float sC = 0.f;
            #pragma unroll
            for (int cc = 0; cc < 20; ++cc) { e[cc] = expf(l[cc] - mC); sC += e[cc]; }
            float mF = l[20], mnF = l[20];
            #pragma unroll
            for (int cc = 21; cc < 40; ++cc) {
                mF = fmaxf(mF, l[cc]);
                mnF = fminf(mnF, l[cc]);
            }
            float sF = 0.f;
            #pragma unroll
            for (int cc = 20; cc < 40; ++cc) sF += expf(l[cc] - mF);
            float pred  = 1.f / sC;                 // max softmax == exp(0)/sum
            float tau   = expf(mnF - mF) / sF;      // min softmax of flow head
            float scale = (pred >= tau + SMARG) ? pred : 0.f;
            float* op = outp + (size_t)(m0 + tid) * NCLS;
            #pragma unroll
            for (int j = 0; j < 5; ++j) {
                v4f o;
                #pragma unroll
                for (int i = 0; i < 4; ++i) o[i] = e[4 * j + i] * scale;
                *(v4f*)(op + 4 * j) = o;
            }
        } else {
            #pragma unroll
            for (int cc = 0; cc < 40; ++cc)
                atomicAdd(Cacc + (size_t)(m0 + tid) * 40 + cc, l[cc]);
        }
    }
}

extern "C" void kernel_launch(void* const* d_in, const int* in_sizes, int n_in,
                              void* d_out, int out_size, void* d_ws, size_t ws_size,
                              hipStream_t stream) {
    const float* X  = (const float*)d_in[0];
    const float* We = (const float*)d_in[1];
    const float* be = (const float*)d_in[2];
    const float* Wc = (const float*)d_in[3];
    const float* bc = (const float*)d_in[4];
    const float* Wf = (const float*)d_in[5];
    const float* bf = (const float*)d_in[6];
    float* out = (float*)d_out;
    float* ws  = (float*)d_ws;
    (void)in_sizes; (void)n_in; (void)out_size; (void)ws_size;

    // K0: zero Weff + fold bias2
    k0_prep<<<dim3(120), dim3(256), 0, stream>>>(Wc, bc, Wf, bf, be, ws);
    // K1: Weff = We @ [Wc|Wf]   (64 row-blocks x 4 block-K splits = 256 blocks)
    panel_gemm<1, false><<<dim3(256), dim3(512), 0, stream>>>(
        We, Wc, Wf, ws + WEFF_OFF, nullptr, nullptr);
    // K2: out = softmax-threshold(X @ Weff + bias2)   (512 blocks x 32 rows)
    panel_gemm<4, true><<<dim3(512), dim3(512), 0, stream>>>(
        X, ws + WEFF_OFF, nullptr, nullptr, ws + BIAS_OFF, out);
}

// Round 4
// 314.464 us; speedup vs baseline: 2.1386x; 1.2517x over previous
//
#include <hip/hip_runtime.h>
#include <math.h>

// Algebraic collapse: out depends on h = X@We + be only through h@Wc and h@Wf.
//   logits[:, 0:20]  = X @ (We@Wc) + (be@Wc + bc)
//   logits[:, 20:40] = X @ (We@Wf) + (be@Wf + bf)
// K0: zero Weff, fold bias2 = [be@Wc + bc | be@Wf + bf]
// K1: Weff = We @ [Wc|Wf]   (panel_gemm<2,false>, 4-way block-K atomic split)
// K2: out  = epilogue(X @ Weff + bias2)   (panel_gemm<8,true>)
//
// Round-4 fix: round 3 still spilled (VGPR_Count=128, 115 MB scratch writes)
// because the design DEMANDED ~230 VGPRs (acc 160 + prefetch 32 + staging 20
// + 8 addr pairs). Now the working set actually fits 128:
//  - 4 col-groups x 2 row-groups: acc2[8][5] = 80 VGPRs (LDS-read traffic
//    unchanged: redundancy per panel row drops 4->2 waves, offsetting the
//    narrower per-thread col span)
//  - X addressed as kernel-arg base + 32-bit element offset (saddr form,
//    ~1 VGPR/addr), no explicit double-prefetch
//  - panel = 256k x 40 cols = 41.3 KB -> 2 blocks/CU (launch_bounds(512,4)),
//    inter-block overlap hides staging barriers
//  - #pragma unroll 1 on the super loop so staging regs never span compute

typedef float v2f __attribute__((ext_vector_type(2)));
typedef float v4f __attribute__((ext_vector_type(4)));

#define KD    2048
#define NCLS  20
#define SMARG 0.31f

// ws layout (floats): Weff[2048*40] row-major, then bias2[40]
#define WEFF_OFF 0
#define BIAS_OFF 81920

#define PROW  516                   // paired panel row stride (512+4), 16B-aligned
#define PANEL_FLOATS (20 * PROW)    // 10320 floats = 41280 B (Hacc 2624 aliases)
#define HROW  164                   // Hacc row: 40 cols x 4 partials + 4 pad

static __device__ __forceinline__ v2f fma2(v2f a, v2f b, v2f c) {
#if __has_builtin(__builtin_elementwise_fma)
    return __builtin_elementwise_fma(a, b, c);   // -> v_pk_fma_f32
#else
    v2f r; r[0] = fmaf(a[0], b[0], c[0]); r[1] = fmaf(a[1], b[1], c[1]); return r;
#endif
}

// ---------------- K0: zero Weff, fold bias2 --------------------------------
__global__ __launch_bounds__(256)
void k0_prep(const float* __restrict__ Wc, const float* __restrict__ bc,
             const float* __restrict__ Wf, const float* __restrict__ bf,
             const float* __restrict__ be, float* __restrict__ ws)
{
    const int b = blockIdx.x;
    const int t = threadIdx.x;
    if (b < 80) {                                   // zero Weff: 80*256*4 = 81920
        v4f z = {0.f, 0.f, 0.f, 0.f};
        *(v4f*)&ws[WEFF_OFF + 4 * (b * 256 + t)] = z;
    } else {                                        // bias2[col], col = b-80
        const int col = b - 80;
        const float* Wp = (col < NCLS) ? Wc : Wf;
        const int cc = (col < NCLS) ? col : col - NCLS;
        float p = 0.f;
        for (int n = t; n < KD; n += 256)
            p = fmaf(be[n], Wp[n * NCLS + cc], p);
        __shared__ float red[256];
        red[t] = p;
        __syncthreads();
        for (int s = 128; s > 0; s >>= 1) {
            if (t < s) red[t] += red[t + s];
            __syncthreads();
        }
        if (t == 0)
            ws[BIAS_OFF + col] = red[0] + ((col < NCLS) ? bc[cc] : bf[cc]);
    }
}

// ---------------- panel GEMM: C[M,40] (+=) A[M,2048] @ B[2048,40] ----------
// Block: 512 thr = 8 waves = 4 col-groups(10 cols) x 2 row-groups(8 rows).
// Lanes span k (2 consecutive k/lane/step of 128 k). X read directly from
// global (saddr + 32-bit voffset), coalesced, touched once. B staged per
// 256-k super into a paired LDS panel [cj][2k] (stride 516) and read as
// contiguous ds_read_b128 (0-conflict). acc2[8][5] v2f -> v_pk_fma_f32;
// each b128 B-fragment feeds 16 fmas. End: 4-stage recursive-halving shfl
// reduce (16-lane groups, static GEPs only), 4 partials -> LDS Hacc ->
// 16 row-lanes finalize.
template<int NSUP, bool FUSED>
__global__ __launch_bounds__(512, 4)
void panel_gemm(const float* __restrict__ A,
                const float* __restrict__ B0,
                const float* __restrict__ B1,
                float* __restrict__ Cacc,
                const float* __restrict__ bias2,
                float* __restrict__ outp)
{
    __shared__ __align__(16) float smem[PANEL_FLOATS];
    const int tid  = threadIdx.x;
    const int lane = tid & 63;
    const int w    = tid >> 6;          // wave 0..7
    const int cg   = w & 3;             // col-group: cols [cg*10, cg*10+10)
    const int rg   = w >> 2;            // row-group: rows [rg*8, rg*8+8)

    int m0, kbase;
    if (FUSED) { m0 = blockIdx.x * 16;              kbase = 0; }
    else       { m0 = (int)(blockIdx.x >> 2) * 16;  kbase = (int)(blockIdx.x & 3) * 512; }

    const unsigned abase = (unsigned)(m0 + rg * 8) * KD + (unsigned)kbase + 2 * lane;

    v2f acc2[8][5];
    #pragma unroll
    for (int r = 0; r < 8; ++r)
        #pragma unroll
        for (int j = 0; j < 5; ++j) acc2[r][j] = (v2f){0.f, 0.f};

    #pragma unroll 1
    for (int sup = 0; sup < NSUP; ++sup) {
        if (sup) __syncthreads();                   // prev-panel readers done
        // ---- stage 256-k paired panel: 2 batches of 5 (v2f load+write) ----
        const int kb = kbase + sup * 256;
        #pragma unroll
        for (int half = 0; half < 2; ++half) {
            v2f sv[5];
            #pragma unroll
            for (int it = 0; it < 5; ++it) {
                const int pi = tid + (half * 5 + it) * 512;   // < 5120 pairs
                const int k = pi / 20, cj = pi % 20;
                unsigned soff;
                const float* bp;
                if (FUSED) { bp = B0; soff = (unsigned)(kb + k) * 40 + 2 * cj; }
                else if (cj < 10) { bp = B0; soff = (unsigned)(kb + k) * 20 + 2 * cj; }
                else { bp = B1; soff = (unsigned)(kb + k) * 20 + 2 * (cj - 10); }
                sv[it] = *(const v2f*)(bp + soff);
            }
            #pragma unroll
            for (int it = 0; it < 5; ++it) {
                const int pi = tid + (half * 5 + it) * 512;
                const int k = pi / 20, cj = pi % 20;
                *(v2f*)(smem + cj * PROW + 2 * k) = sv[it];
            }
        }
        __syncthreads();
        // ---- 2 compute steps of 128 k each ----
        #pragma unroll
        for (int st = 0; st < 2; ++st) {
            v2f xv[8];
            #pragma unroll
            for (int r = 0; r < 8; ++r)             // saddr + 32-bit voffset
                xv[r] = *(const v2f*)(A + (abase + (unsigned)(r * KD + sup * 256 + st * 128)));
            const float* pb = smem + cg * (5 * PROW) + st * 256 + 4 * lane;
            #pragma unroll
            for (int j2 = 0; j2 < 5; ++j2) {
                v4f bv  = *(const v4f*)(pb + j2 * PROW);   // contiguous b128
                v2f blo = {bv[0], bv[1]}, bhi = {bv[2], bv[3]};
                #pragma unroll
                for (int r = 0; r < 8; ++r) {
                    v2f x0 = {xv[r][0], xv[r][0]};
                    v2f x1 = {xv[r][1], xv[r][1]};
                    acc2[r][j2] = fma2(x1, bhi, fma2(x0, blo, acc2[r][j2]));
                }
            }
        }
    }

    __syncthreads();                                // panel dead; alias as Hacc

    // ---- recursive-halving reduce-scatter over 16-lane groups -------------
    // 80 values/lane, flat index i = r*10 + colInCg; ALL accesses are
    // compile-time-constant GEPs on acc2 (stays in VGPRs).
#define V(i) acc2[(i) / 10][((i) % 10) >> 1][(i) & 1]
    {
        const bool u1 = lane & 1;
        #pragma unroll
        for (int i = 0; i < 40; ++i) {
            float snd = u1 ? V(i) : V(i + 40);
            float rcv = __shfl_xor(snd, 1, 64);
            V(i) = (u1 ? V(i + 40) : V(i)) + rcv;
        }
        const bool u2 = lane & 2;
        #pragma unroll
        for (int i = 0; i < 20; ++i) {
            float snd = u2 ? V(i) : V(i + 20);
            float rcv = __shfl_xor(snd, 2, 64);
            V(i) = (u2 ? V(i + 20) : V(i)) + rcv;
        }
        const bool u4 = lane & 4;
        #pragma unroll
        for (int i = 0; i < 10; ++i) {
            float snd = u4 ? V(i) : V(i + 10);
            float rcv = __shfl_xor(snd, 4, 64);
            V(i) = (u4 ? V(i + 10) : V(i)) + rcv;
        }
        const bool u8 = lane & 8;
        #pragma unroll
        for (int i = 0; i < 5; ++i) {
            float snd = u8 ? V(i) : V(i + 5);
            float rcv = __shfl_xor(snd, 8, 64);
            V(i) = (u8 ? V(i + 5) : V(i)) + rcv;
        }
    }
    // lane holds flat indices base..base+4, base = 40a+20b+10c+5d (lane bits)
    {
        const int a = lane & 1, b = (lane >> 1) & 1;
        const int c = (lane >> 2) & 1, d = (lane >> 3) & 1;
        const int g  = lane >> 4;                   // partial group 0..3
        const int r0 = 4 * a + 2 * b + c;           // row within row-group
        const int c0 = cg * 10 + 5 * d;             // first col
        #pragma unroll
        for (int t = 0; t < 5; ++t)
            smem[(rg * 8 + r0) * HROW + (c0 + t) * 4 + g] = V(t);
    }
#undef V
    __syncthreads();

    if (tid < 16) {
        float l[40];
        #pragma unroll
        for (int cc = 0; cc < 40; ++cc) {
            v4f q = *(const v4f*)(smem + tid * HROW + cc * 4);
            l[cc] = (q[0] + q[1]) + (q[2] + q[3]);
        }
        if (FUSED) {
            #pragma unroll
            for (int cc = 0; cc < 40; ++cc) l[cc] += bias2[cc];
            float mC = l[0];
            #pragma unroll
            for (int cc = 1; cc < 20; ++cc) mC = fmaxf(mC, l[cc]);
            float e[20];
            float sC = 0.f;
            #pragma unroll
            for (int cc = 0; cc < 20; ++cc) { e[cc] = expf(l[cc] - mC); sC += e[cc]; }
            float mF = l[20], mnF = l[20];
            #pragma unroll
            for (int cc = 21; cc < 40; ++cc) {
                mF = fmaxf(mF, l[cc]);
                mnF = fminf(mnF, l[cc]);
            }
            float sF = 0.f;
            #pragma unroll
            for (int cc = 20; cc < 40; ++cc) sF += expf(l[cc] - mF);
            float pred  = 1.f / sC;                 // max softmax == exp(0)/sum
            float tau   = expf(mnF - mF) / sF;      // min softmax of flow head
            float scale = (pred >= tau + SMARG) ? pred : 0.f;
            float* op = outp + (size_t)(m0 + tid) * NCLS;
            #pragma unroll
            for (int j = 0; j < 5; ++j) {
                v4f o;
                #pragma unroll
                for (int i = 0; i < 4; ++i) o[i] = e[4 * j + i] * scale;
                *(v4f*)(op + 4 * j) = o;
            }
        } else {
            #pragma unroll
            for (int cc = 0; cc < 40; ++cc)
                atomicAdd(Cacc + (size_t)(m0 + tid) * 40 + cc, l[cc]);
        }
    }
}

extern "C" void kernel_launch(void* const* d_in, const int* in_sizes, int n_in,
                              void* d_out, int out_size, void* d_ws, size_t ws_size,
                              hipStream_t stream) {
    const float* X  = (const float*)d_in[0];
    const float* We = (const float*)d_in[1];
    const float* be = (const float*)d_in[2];
    const float* Wc = (const float*)d_in[3];
    const float* bc = (const float*)d_in[4];
    const float* Wf = (const float*)d_in[5];
    const float* bf = (const float*)d_in[6];
    float* out = (float*)d_out;
    float* ws  = (float*)d_ws;
    (void)in_sizes; (void)n_in; (void)out_size; (void)ws_size;

    // K0: zero Weff + fold bias2
    k0_prep<<<dim3(120), dim3(256), 0, stream>>>(Wc, bc, Wf, bf, be, ws);
    // K1: Weff = We @ [Wc|Wf]  (128 row-blocks x 4 block-K splits = 512 blocks)
    panel_gemm<2, false><<<dim3(512), dim3(512), 0, stream>>>(
        We, Wc, Wf, ws + WEFF_OFF, nullptr, nullptr);
    // K2: out = softmax-threshold(X @ Weff + bias2)  (1024 blocks x 16 rows)
    panel_gemm<8, true><<<dim3(1024), dim3(512), 0, stream>>>(
        X, ws + WEFF_OFF, nullptr, nullptr, ws + BIAS_OFF, out);
}